// Round 17
// baseline (82.071 us; speedup 1.0000x reference)
//
#include <hip/hip_runtime.h>

#define N2 (768 * 768)
#define NH 32
#define PPB 128      // pairs per block; 4608 blocks
#define TPB 256

typedef float v4f __attribute__((ext_vector_type(4)));

// ---------- Pass 1: parallel block-boundary search ----------
// key(e) = (coeff==0 ? INT_MAX : pair[e]) is globally sorted (pair_idx sorted
// ascending over valid prefix, padding coeff==0 at the tail). bnd[j] =
// lower_bound(key, j*PPB). 4609 independent searches, fully parallel.
__global__ void bounds_kernel(const int* __restrict__ pair,
                              const float* __restrict__ coeff,
                              int* __restrict__ bnd, int M) {
    int j = blockIdx.x * blockDim.x + threadIdx.x;
    if (j > N2 / PPB) return;
    int target = j * PPB;
    int lo = 0, hi = M;
    while (lo < hi) {
        int mid = (lo + hi) >> 1;
        int key = (coeff[mid] == 0.f) ? 0x7fffffff : pair[mid];
        if (key < target) lo = mid + 1; else hi = mid;
    }
    bnd[j] = lo;
}

// ---------- Pass 2: fused accumulate + expand ----------
// out[h,p] = b[h]*S0[p] + sum_k W[h][k]*S[k][p], S0 = sum_e c_e,
// S[k] = sum_e c_e * ea[node_e][k] over pair p's entries.
// Single-touch entry pass: each thread takes 4 consecutive entries
// (int4/int4/float4, 16B/lane coalesced; M%4==0 so group loads are
// in-bounds), merges equal-key runs in registers, flushes 5-float partials
// into acc[5][PPB] via LDS float atomics (all cross-thread/wave merging for
// free). Entries outside [s0,s1) are masked to c=0 (valid coeffs strictly
// positive -> zero contributions exact); flushes are guarded by key-in-range
// so neighbor-block keys never touch LDS. Padding (pair==0,c==0) adds exact
// zeros. One barrier, then fused 32-channel expansion: 4 v4f NT stores per
// thread, every output element written exactly once; pairs with no entries
// keep acc==0 -> exact zeros, matching segment_sum.
__global__ __launch_bounds__(256) void fused_kernel(
    const int* __restrict__ pair, const int* __restrict__ node,
    const float* __restrict__ coeff, const float* __restrict__ ea,
    const float* __restrict__ W, const float* __restrict__ bias,
    const int* __restrict__ bnd, float* __restrict__ out)
{
    __shared__ float acc[5][PPB];        // 2.5 KB
    __shared__ float sW[NH * 4];
    __shared__ float sBias[NH];

    const int t = threadIdx.x;
    const int p0 = blockIdx.x * PPB;

    if (t < NH * 4) sW[t] = W[t];
    if (t < NH) sBias[t] = bias[t];
    {
        float* af = &acc[0][0];
        for (int i = t; i < 5 * PPB; i += TPB) af[i] = 0.f;
    }
    __syncthreads();

    const int s0 = bnd[blockIdx.x], s1 = bnd[blockIdx.x + 1];
    const int g0 = s0 >> 2, g1 = (s1 + 3) >> 2;   // 4-entry group range

#define FLUSH()                                                               \
    {                                                                         \
        const unsigned q = (unsigned)(curkey - p0);                           \
        if (q < PPB) {                                                        \
            atomicAdd(&acc[0][q], v0); atomicAdd(&acc[1][q], v1);             \
            atomicAdd(&acc[2][q], v2); atomicAdd(&acc[3][q], v3);             \
            atomicAdd(&acc[4][q], v4);                                        \
        }                                                                     \
    }
#define STEP(KEY, ND, CC)                                                     \
    if ((KEY) != curkey) { FLUSH(); curkey = (KEY); v0 = v1 = v2 = v3 = v4 = 0.f; } \
    {                                                                         \
        const float4 e = *reinterpret_cast<const float4*>(ea + (ND) * 4);     \
        v0 += (CC); v1 += (CC) * e.x; v2 += (CC) * e.y;                       \
        v3 += (CC) * e.z; v4 += (CC) * e.w;                                   \
    }

    for (int g = g0 + t; g < g1; g += TPB) {
        const int e0 = g << 2;
        const int4   pk = reinterpret_cast<const int4*>(pair)[g];
        const int4   nd = reinterpret_cast<const int4*>(node)[g];
        const float4 c4 = reinterpret_cast<const float4*>(coeff)[g];
        const float c0 = (e0     >= s0 && e0     < s1) ? c4.x : 0.f;
        const float c1 = (e0 + 1 >= s0 && e0 + 1 < s1) ? c4.y : 0.f;
        const float c2 = (e0 + 2 >= s0 && e0 + 2 < s1) ? c4.z : 0.f;
        const float c3 = (e0 + 3 >= s0 && e0 + 3 < s1) ? c4.w : 0.f;

        int curkey = pk.x;
        float v0, v1, v2, v3, v4;
        {
            const float4 e = *reinterpret_cast<const float4*>(ea + nd.x * 4);
            v0 = c0; v1 = c0 * e.x; v2 = c0 * e.y; v3 = c0 * e.z; v4 = c0 * e.w;
        }
        STEP(pk.y, nd.y, c1)
        STEP(pk.z, nd.z, c2)
        STEP(pk.w, nd.w, c3)
        FLUSH()
    }
#undef STEP
#undef FLUSH
    __syncthreads();

    // expansion: wave w (0..3), lane l; g = l&31 -> pairs 4g..4g+3;
    // channels h = w*8 + (l>>5)*4 + j, j in 0..3. 512B/wave-instr NT stores.
    {
        const int l = t & 63, w = t >> 6;
        const int g = l & 31, half = l >> 5;
        const v4f b0 = *reinterpret_cast<const v4f*>(&acc[0][4 * g]);
        const v4f b1 = *reinterpret_cast<const v4f*>(&acc[1][4 * g]);
        const v4f b2 = *reinterpret_cast<const v4f*>(&acc[2][4 * g]);
        const v4f b3 = *reinterpret_cast<const v4f*>(&acc[3][4 * g]);
        const v4f b4 = *reinterpret_cast<const v4f*>(&acc[4][4 * g]);
        const size_t op = (size_t)p0 + 4 * g;
#pragma unroll
        for (int j = 0; j < 4; ++j) {
            const int h = w * 8 + half * 4 + j;
            const float bb = sBias[h], w0 = sW[h * 4], w1 = sW[h * 4 + 1],
                        w2 = sW[h * 4 + 2], w3 = sW[h * 4 + 3];
            v4f o = bb * b0 + w0 * b1 + w1 * b2 + w2 * b3 + w3 * b4;
            __builtin_nontemporal_store(o, reinterpret_cast<v4f*>(out + (size_t)h * N2 + op));
        }
    }
}

extern "C" void kernel_launch(void* const* d_in, const int* in_sizes, int n_in,
                              void* d_out, int out_size, void* d_ws, size_t ws_size,
                              hipStream_t stream) {
    // inputs: 0=x 1=edge_attr 2=W 3=b 4=edge_idx 5=pair_idx 6=node_idx 7=coeff 8=num_nodes
    const float* ea    = (const float*)d_in[1];
    const float* W     = (const float*)d_in[2];
    const float* b     = (const float*)d_in[3];
    const int*   pair  = (const int*)d_in[5];
    const int*   node  = (const int*)d_in[6];
    const float* coeff = (const float*)d_in[7];
    float* out = (float*)d_out;
    int M = in_sizes[5];

    int* bnd = (int*)d_ws;   // N2/PPB + 1 = 4609 ints

    bounds_kernel<<<(N2 / PPB + 1 + 255) / 256, 256, 0, stream>>>(pair, coeff, bnd, M);

    fused_kernel<<<N2 / PPB, TPB, 0, stream>>>(pair, node, coeff, ea, W, b, bnd, out);
}

// Round 19
// 59.987 us; speedup vs baseline: 1.3681x; 1.3681x over previous
//
#include <hip/hip_runtime.h>

#define N2 (768 * 768)
#define NH 32
#define PPC 32               // pairs per chunk
#define NCH 8                // chunks per block -> 256 pairs/block; 2304 blocks
#define PPB (PPC * NCH)
#define TPB 256              // 8 threads per pair
#define CAP 1024             // ent slots per buffer (8 KB each)

typedef float v4f __attribute__((ext_vector_type(4)));

// ---------- Pass 1: parallel chunk-boundary search ----------
// key(e) = (coeff==0 ? INT_MAX : pair[e]) is globally sorted (pair_idx sorted
// ascending over valid prefix, padding coeff==0 at tail). bnd[j] =
// lower_bound(key, j*PPC). 18433 independent searches, fully parallel.
__global__ void bounds_kernel(const int* __restrict__ pair,
                              const float* __restrict__ coeff,
                              int* __restrict__ bnd, int M) {
    int j = blockIdx.x * blockDim.x + threadIdx.x;
    if (j > N2 / PPC) return;
    int target = j * PPC;
    int lo = 0, hi = M;
    while (lo < hi) {
        int mid = (lo + hi) >> 1;
        int key = (coeff[mid] == 0.f) ? 0x7fffffff : pair[mid];
        if (key < target) lo = mid + 1; else hi = mid;
    }
    bnd[j] = lo;
}

// Stage one 4-entry group into ent buffer + tagged run boundaries.
__device__ __forceinline__ void stage_group(
    float2* entbuf, int* psb, int* peb,
    int4 pk, int4 nd, float4 c4, int prevp, int nextp,
    int gi, int a0, int s0c, int s1c, int ctag, int np0)
{
    const int i0 = gi << 2;
    v4f w0; w0.x = c4.x; w0.y = __int_as_float(nd.x);
            w0.z = c4.y; w0.w = __int_as_float(nd.y);
    v4f w1; w1.x = c4.z; w1.y = __int_as_float(nd.z);
            w1.z = c4.w; w1.w = __int_as_float(nd.w);
    *reinterpret_cast<v4f*>(&entbuf[i0])     = w0;
    *reinterpret_cast<v4f*>(&entbuf[i0 + 2]) = w1;
    const int e0 = a0 + i0;
    const int pk6[6] = { prevp, pk.x, pk.y, pk.z, pk.w, nextp };
#pragma unroll
    for (int j = 0; j < 4; ++j) {
        const int e = e0 + j;
        const int pp = pk6[j + 1];
        if (e >= s0c && e < s1c) {
            if (e == s0c || pk6[j] != pp) psb[pp - np0] = (ctag << 14) | (e - a0);
            if (e == s1c - 1 || pk6[j + 2] != pp) peb[pp - np0] = (ctag << 14) | (e - a0 + 1);
        }
    }
}

// ---------- Pass 2: pipelined stage/walk/expand ----------
// Per iteration: issue chunk c+1 global loads into held regs (lanes t<ngN
// only); walk chunk c from LDS (8 thr/pair, ea 12KB L1-hot); shfl merge;
// barrier; expand chunk c (NT stores); ds_write held regs into the other
// buffer (HBM/L3 latency covered by walk+expand); barrier. Epoch tags
// (chunk<<14 | rel) make stale ps/pe harmless. Every output element written
// exactly once; pairs with no entries -> tag mismatch -> exact zeros.
__global__ __launch_bounds__(256) void fused_kernel(
    const int* __restrict__ pair, const int* __restrict__ node,
    const float* __restrict__ coeff, const float* __restrict__ ea,
    const float* __restrict__ W, const float* __restrict__ bias,
    const int* __restrict__ bnd, float* __restrict__ out, int M)
{
    __shared__ float2 ent[2][CAP];       // 16 KB
    __shared__ int ps[2][PPC], pe[2][PPC];
    __shared__ float sum[5][PPC];
    __shared__ int sBnd[NCH + 1];
    __shared__ float sW[NH * 4];
    __shared__ float sBias[NH];

    const int t = threadIdx.x;
    const int pbase = blockIdx.x * PPB;
    const int cbase = blockIdx.x * NCH;

    if (t < NH * 4) sW[t] = W[t];
    if (t < NH) sBias[t] = bias[t];
    if (t <= NCH) sBnd[t] = bnd[cbase + t];
    if (t < PPC) { ps[0][t] = -1; pe[0][t] = -1; ps[1][t] = -1; pe[1][t] = -1; }
    __syncthreads();         // init visible BEFORE any staging writes (race fix #1)

    // prologue: stage chunk 0 into buf 0 (immediate)
    int cs0 = sBnd[0], cs1 = sBnd[1];
    bool curStaged = (cs1 - (cs0 & ~3)) <= CAP;
    if (curStaged) {
        const int a0 = cs0 & ~3;
        const int gN = (cs1 - a0 + 3) >> 2;
        int4 pk = {0,0,0,0}, nd = {0,0,0,0};
        float4 c4 = {0.f,0.f,0.f,0.f};
        if (t < gN) {
            const int g = (a0 >> 2) + t;
            pk = reinterpret_cast<const int4*>(pair)[g];
            nd = reinterpret_cast<const int4*>(node)[g];
            c4 = reinterpret_cast<const float4*>(coeff)[g];
        }
        // all lanes execute shfls; only t<gN lanes' results are used
        int prevp = __shfl_up(pk.w, 1);
        int nextp = __shfl_down(pk.x, 1);
        const int e0 = a0 + (t << 2);
        if ((t & 63) == 0)  prevp = (e0 > 0) ? pair[e0 - 1] : -1;
        if ((t & 63) == 63) nextp = (e0 + 4 < M) ? pair[e0 + 4] : -1;
        if (t < gN)
            stage_group(ent[0], ps[0], pe[0], pk, nd, c4, prevp, nextp,
                        t, a0, cs0, cs1, 0, pbase);
    }
    __syncthreads();

    int cur = 0;
    for (int c = 0; c < NCH; ++c) {
        const int nb = cur ^ 1;
        // ---- A: issue next-chunk loads (no wait); lanes t<ngN only (fix #2)
        int4 hpk = {0,0,0,0}, hnd = {0,0,0,0};
        float4 hc4 = {0.f,0.f,0.f,0.f};
        int hpv = -1, hnx = -1, na0 = 0, ngN = 0, ns1 = cs1;
        const int ns0 = cs1;
        bool nStaged = false;
        if (c + 1 < NCH) {
            ns1 = sBnd[c + 2];
            na0 = ns0 & ~3;
            nStaged = (ns1 - na0) <= CAP;
            ngN = (ns1 - na0 + 3) >> 2;
            if (nStaged && t < ngN) {
                const int g = (na0 >> 2) + t;
                hpk = reinterpret_cast<const int4*>(pair)[g];
                hnd = reinterpret_cast<const int4*>(node)[g];
                hc4 = reinterpret_cast<const float4*>(coeff)[g];
                const int e0 = na0 + (t << 2);
                if ((t & 63) == 0)  hpv = (e0 > 0) ? pair[e0 - 1] : -1;
                if ((t & 63) == 63) hnx = (e0 + 4 < M) ? pair[e0 + 4] : -1;
            }
        }
        // ---- B: walk chunk c ----
        const int q = t >> 3, sub = t & 7;
        float a0f = 0.f, a1f = 0.f, a2f = 0.f, a3f = 0.f, a4f = 0.f;
        if (curStaged) {
            const int vs = ps[cur][q], ve = pe[cur][q];
            const int s = ((vs >> 14) == c) ? (vs & 0x3fff) : 0;
            const int e = ((ve >> 14) == c) ? (ve & 0x3fff) : 0;
            for (int k = s + sub; k < e; k += 8) {
                const float2 en = ent[cur][k];
                const float cc = en.x;
                const int ndx = __float_as_int(en.y);
                const float4 v = *reinterpret_cast<const float4*>(ea + ndx * 4);
                a0f += cc; a1f += cc * v.x; a2f += cc * v.y; a3f += cc * v.z; a4f += cc * v.w;
            }
        } else {
            // rare overflow: per-pair bounds via binary search, walk global
            const int tgt = pbase + c * PPC + q;
            int lo = cs0, hi = cs1;
            while (lo < hi) { int mid = (lo + hi) >> 1; if (pair[mid] < tgt) lo = mid + 1; else hi = mid; }
            int s = lo; hi = cs1;
            while (lo < hi) { int mid = (lo + hi) >> 1; if (pair[mid] <= tgt) lo = mid + 1; else hi = mid; }
            for (int k = s + sub; k < lo; k += 8) {
                const float cc = coeff[k];
                const float4 v = *reinterpret_cast<const float4*>(ea + node[k] * 4);
                a0f += cc; a1f += cc * v.x; a2f += cc * v.y; a3f += cc * v.z; a4f += cc * v.w;
            }
        }
        // ---- C: merge 8 lanes/pair ----
#pragma unroll
        for (int d = 1; d < 8; d <<= 1) {
            a0f += __shfl_xor(a0f, d); a1f += __shfl_xor(a1f, d);
            a2f += __shfl_xor(a2f, d); a3f += __shfl_xor(a3f, d);
            a4f += __shfl_xor(a4f, d);
        }
        if (sub == 0) {
            sum[0][q] = a0f; sum[1][q] = a1f; sum[2][q] = a2f;
            sum[3][q] = a3f; sum[4][q] = a4f;
        }
        __syncthreads();     // D: sum valid; ent[nb]/ps[nb] free
        // ---- F: expand chunk c (NT stores) ----
        {
            const int g = t & 7, h = t >> 3;
            const v4f b0 = *reinterpret_cast<const v4f*>(&sum[0][4 * g]);
            const v4f b1 = *reinterpret_cast<const v4f*>(&sum[1][4 * g]);
            const v4f b2 = *reinterpret_cast<const v4f*>(&sum[2][4 * g]);
            const v4f b3 = *reinterpret_cast<const v4f*>(&sum[3][4 * g]);
            const v4f b4 = *reinterpret_cast<const v4f*>(&sum[4][4 * g]);
            const float bb = sBias[h], w0 = sW[h * 4], w1 = sW[h * 4 + 1],
                        w2 = sW[h * 4 + 2], w3 = sW[h * 4 + 3];
            v4f o = bb * b0 + w0 * b1 + w1 * b2 + w2 * b3 + w3 * b4;
            __builtin_nontemporal_store(o,
                reinterpret_cast<v4f*>(out + (size_t)h * N2 + pbase + c * PPC + 4 * g));
        }
        // ---- E: write held regs into buffer nb ----
        if (c + 1 < NCH && nStaged && ngN > 0) {
            // all lanes execute shfls; only t<ngN lanes write
            int prevp = __shfl_up(hpk.w, 1);
            int nextp = __shfl_down(hpk.x, 1);
            if ((t & 63) == 0)  prevp = hpv;
            if ((t & 63) == 63) nextp = hnx;
            if (t < ngN)
                stage_group(ent[nb], ps[nb], pe[nb], hpk, hnd, hc4, prevp, nextp,
                            t, na0, ns0, ns1, c + 1, pbase + (c + 1) * PPC);
        }
        __syncthreads();     // G: staging visible; sum free for next iter
        cur = nb; cs0 = ns0; cs1 = ns1; curStaged = nStaged;
    }
}

extern "C" void kernel_launch(void* const* d_in, const int* in_sizes, int n_in,
                              void* d_out, int out_size, void* d_ws, size_t ws_size,
                              hipStream_t stream) {
    // inputs: 0=x 1=edge_attr 2=W 3=b 4=edge_idx 5=pair_idx 6=node_idx 7=coeff 8=num_nodes
    const float* ea    = (const float*)d_in[1];
    const float* W     = (const float*)d_in[2];
    const float* b     = (const float*)d_in[3];
    const int*   pair  = (const int*)d_in[5];
    const int*   node  = (const int*)d_in[6];
    const float* coeff = (const float*)d_in[7];
    float* out = (float*)d_out;
    int M = in_sizes[5];

    int* bnd = (int*)d_ws;   // N2/PPC + 1 = 18433 ints

    bounds_kernel<<<(N2 / PPC + 1 + 255) / 256, 256, 0, stream>>>(pair, coeff, bnd, M);

    fused_kernel<<<N2 / PPB, TPB, 0, stream>>>(pair, node, coeff, ea, W, b, bnd, out, M);
}

// Round 20
// 48.232 us; speedup vs baseline: 1.7016x; 1.2437x over previous
//
#include <hip/hip_runtime.h>

#define N2 (768 * 768)
#define NH 32
#define PPB 64       // pairs per block; 9216 blocks
#define TPB 256      // 4 threads per pair, 4 waves
#define CAP 1664     // staged LDS slots (13.3 KB); global-walk fallback beyond

typedef float v4f __attribute__((ext_vector_type(4)));

// ---------- Pass 1: parallel block-boundary search ----------
// key(e) = (coeff==0 ? INT_MAX : pair[e]) is globally sorted (pair_idx sorted
// ascending over valid prefix, padding coeff==0 at the tail). bnd[j] =
// lower_bound(key, j*PPB). 9217 independent searches, fully parallel.
__global__ void bounds_kernel(const int* __restrict__ pair,
                              const float* __restrict__ coeff,
                              int* __restrict__ bnd, int M) {
    int j = blockIdx.x * blockDim.x + threadIdx.x;
    if (j > N2 / PPB) return;
    int target = j * PPB;
    int lo = 0, hi = M;
    while (lo < hi) {
        int mid = (lo + hi) >> 1;
        int key = (coeff[mid] == 0.f) ? 0x7fffffff : pair[mid];
        if (key < target) lo = mid + 1; else hi = mid;
    }
    bnd[j] = lo;
}

// ---------- Pass 2: fused stage + walk + expand (R16 structure) ----------
// out[h,p] = b[h]*S0[p] + sum_k W[h][k]*S[k][p] over pair p's entry segment.
// Vectorized stage (int4/int4/float4, 16B/lane; window aligned to 4; M%4==0
// keeps loads in-bounds), run boundaries from registers (2 scalar L1-hit
// neighbor loads), two ds_write_b128 per 4 entries. 4 threads/pair walk
// 2 adjacent entries per iteration (stride 8) from LDS -> half the dependent
// iterations, 2 independent gathers in flight (ea 12KB L1-hot). 2-step
// shfl_xor merge, sums to dedicated LDS buffer, expansion = 2 v4f NT stores
// per thread. Every output element written exactly once; missing pairs keep
// ps=pe=0 -> exact zeros, matching segment_sum.
__global__ __launch_bounds__(256) void fused_kernel(
    const int* __restrict__ pair, const int* __restrict__ node,
    const float* __restrict__ coeff, const float* __restrict__ ea,
    const float* __restrict__ W, const float* __restrict__ bias,
    const int* __restrict__ bnd, float* __restrict__ out, int M)
{
    __shared__ float2 ent[CAP];          // 13.3 KB
    __shared__ float sum[5][PPB];        // 1.25 KB
    __shared__ int ps[PPB], pe[PPB];
    __shared__ float sW[NH * 4];
    __shared__ float sBias[NH];

    const int t = threadIdx.x;
    const int p0 = blockIdx.x * PPB;

    if (t < NH * 4) sW[t] = W[t];
    if (t < NH) sBias[t] = bias[t];
    if (t < PPB) { ps[t] = 0; pe[t] = 0; }
    __syncthreads();

    const int s0 = bnd[blockIdx.x], s1 = bnd[blockIdx.x + 1];
    const int s0a = s0 & ~3;             // 4-aligned staging base
    const int cntA = s1 - s0a;           // staged span
    const bool staged = (cntA <= CAP);   // block-uniform

    if (staged) {
        for (int i4 = t; (i4 << 2) < cntA; i4 += TPB) {
            const int e0 = s0a + (i4 << 2);
            const int4   p4 = reinterpret_cast<const int4*>(pair)[e0 >> 2];
            const int4   n4 = reinterpret_cast<const int4*>(node)[e0 >> 2];
            const float4 c4 = reinterpret_cast<const float4*>(coeff)[e0 >> 2];
            v4f w0; w0.x = c4.x; w0.y = __int_as_float(n4.x);
                    w0.z = c4.y; w0.w = __int_as_float(n4.y);
            v4f w1; w1.x = c4.z; w1.y = __int_as_float(n4.z);
                    w1.z = c4.w; w1.w = __int_as_float(n4.w);
            *reinterpret_cast<v4f*>(&ent[i4 << 2])       = w0;
            *reinterpret_cast<v4f*>(&ent[(i4 << 2) + 2]) = w1;
            const int prevp = (e0 > 0) ? pair[e0 - 1] : -1;
            const int nextp = (e0 + 4 < M) ? pair[e0 + 4] : -1;
            const int pk[6] = { prevp, p4.x, p4.y, p4.z, p4.w, nextp };
#pragma unroll
            for (int j = 0; j < 4; ++j) {
                const int e = e0 + j;
                const int pp = pk[j + 1];
                if (e >= s0 && e < s1) {
                    if (e == s0 || pk[j] != pp) ps[pp - p0] = e;
                    if (e == s1 - 1 || pk[j + 2] != pp) pe[pp - p0] = e + 1;
                }
            }
        }
    } else {
        const int cnt = s1 - s0;
        for (int i = t; i < cnt; i += TPB) {
            int e = s0 + i;
            int pp = pair[e];
            if (i == 0 || pair[e - 1] != pp) ps[pp - p0] = e;
            if (i == cnt - 1 || pair[e + 1] != pp) pe[pp - p0] = e + 1;
        }
    }
    __syncthreads();

    // 4 threads/pair, 2 adjacent entries per iteration (stride 8):
    // q = t>>2, sub = t&3 -> entries s+2sub, s+2sub+1, s+2sub+8, ...
    const int q = t >> 2, sub = t & 3;
    float a0 = 0.f, a1 = 0.f, a2 = 0.f, a3 = 0.f, a4 = 0.f;
    float b0s = 0.f, b1s = 0.f, b2s = 0.f, b3s = 0.f, b4s = 0.f;
    {
        const int e = pe[q];
        int k = ps[q] + (sub << 1);
        if (staged) {
            for (; k < e; k += 8) {
                const float2 enA = ent[k - s0a];
                const float ccA = enA.x;
                const int ndA = __float_as_int(enA.y);
                const float4 vA = *reinterpret_cast<const float4*>(ea + ndA * 4);
                a0 += ccA; a1 += ccA * vA.x; a2 += ccA * vA.y; a3 += ccA * vA.z; a4 += ccA * vA.w;
                if (k + 1 < e) {
                    const float2 enB = ent[k + 1 - s0a];
                    const float ccB = enB.x;
                    const int ndB = __float_as_int(enB.y);
                    const float4 vB = *reinterpret_cast<const float4*>(ea + ndB * 4);
                    b0s += ccB; b1s += ccB * vB.x; b2s += ccB * vB.y; b3s += ccB * vB.z; b4s += ccB * vB.w;
                }
            }
        } else {
            for (; k < e; k += 8) {
                const float ccA = coeff[k];
                const float4 vA = *reinterpret_cast<const float4*>(ea + node[k] * 4);
                a0 += ccA; a1 += ccA * vA.x; a2 += ccA * vA.y; a3 += ccA * vA.z; a4 += ccA * vA.w;
                if (k + 1 < e) {
                    const float ccB = coeff[k + 1];
                    const float4 vB = *reinterpret_cast<const float4*>(ea + node[k + 1] * 4);
                    b0s += ccB; b1s += ccB * vB.x; b2s += ccB * vB.y; b3s += ccB * vB.z; b4s += ccB * vB.w;
                }
            }
        }
    }
    a0 += b0s; a1 += b1s; a2 += b2s; a3 += b3s; a4 += b4s;
#pragma unroll
    for (int d = 1; d < 4; d <<= 1) {
        a0 += __shfl_xor(a0, d); a1 += __shfl_xor(a1, d); a2 += __shfl_xor(a2, d);
        a3 += __shfl_xor(a3, d); a4 += __shfl_xor(a4, d);
    }
    if (sub == 0) {
        sum[0][q] = a0; sum[1][q] = a1; sum[2][q] = a2;
        sum[3][q] = a3; sum[4][q] = a4;
    }
    __syncthreads();

    // expansion: wave w, lane l; group g = l&15 -> pairs 4g..4g+3;
    // channels h = w*8 + (l>>4)*2 + j, j in {0,1}.
    {
        const int l = t & 63, w = t >> 6;
        const int g = l & 15, quad = l >> 4;
        const v4f c0 = *reinterpret_cast<const v4f*>(&sum[0][4 * g]);
        const v4f c1 = *reinterpret_cast<const v4f*>(&sum[1][4 * g]);
        const v4f c2 = *reinterpret_cast<const v4f*>(&sum[2][4 * g]);
        const v4f c3 = *reinterpret_cast<const v4f*>(&sum[3][4 * g]);
        const v4f c4 = *reinterpret_cast<const v4f*>(&sum[4][4 * g]);
        const size_t op = (size_t)p0 + 4 * g;
#pragma unroll
        for (int j = 0; j < 2; ++j) {
            const int h = w * 8 + quad * 2 + j;
            const float bb = sBias[h], w0 = sW[h * 4], w1 = sW[h * 4 + 1],
                        w2 = sW[h * 4 + 2], w3 = sW[h * 4 + 3];
            v4f o = bb * c0 + w0 * c1 + w1 * c2 + w2 * c3 + w3 * c4;
            __builtin_nontemporal_store(o, reinterpret_cast<v4f*>(out + (size_t)h * N2 + op));
        }
    }
}

extern "C" void kernel_launch(void* const* d_in, const int* in_sizes, int n_in,
                              void* d_out, int out_size, void* d_ws, size_t ws_size,
                              hipStream_t stream) {
    // inputs: 0=x 1=edge_attr 2=W 3=b 4=edge_idx 5=pair_idx 6=node_idx 7=coeff 8=num_nodes
    const float* ea    = (const float*)d_in[1];
    const float* W     = (const float*)d_in[2];
    const float* b     = (const float*)d_in[3];
    const int*   pair  = (const int*)d_in[5];
    const int*   node  = (const int*)d_in[6];
    const float* coeff = (const float*)d_in[7];
    float* out = (float*)d_out;
    int M = in_sizes[5];

    int* bnd = (int*)d_ws;   // N2/PPB + 1 = 9217 ints

    bounds_kernel<<<(N2 / PPB + 1 + 255) / 256, 256, 0, stream>>>(pair, coeff, bnd, M);

    fused_kernel<<<N2 / PPB, TPB, 0, stream>>>(pair, node, coeff, ea, W, b, bnd, out, M);
}